// Round 2
// baseline (4209.615 us; speedup 1.0000x reference)
//
#include <hip/hip_runtime.h>

typedef unsigned short u16;
typedef __attribute__((ext_vector_type(8))) short bf16x8;
typedef __attribute__((ext_vector_type(4))) float f32x4;

// ---------- helpers ----------
__device__ __forceinline__ float bf2f(u16 u) {
  union { unsigned u; float f; } c; c.u = ((unsigned)u) << 16; return c.f;
}
__device__ __forceinline__ u16 f2bf(float f) {
  union { float f; unsigned u; } c; c.f = f;
  unsigned r = (c.u + 0x7fffu + ((c.u >> 16) & 1u)) >> 16;
  return (u16)r;
}
__device__ __forceinline__ void gload16(const u16* g, u16* l) {
  __builtin_amdgcn_global_load_lds((__attribute__((address_space(1))) void*)(g),
                                   (__attribute__((address_space(3))) void*)(l), 16, 0, 0);
}

// ---------- transpose + fp32->bf16 cast:  in[R][C] fp32 -> out[C][R] bf16 ----------
__global__ __launch_bounds__(256) void tcast(const float* __restrict__ in,
                                             u16* __restrict__ out, int R, int C) {
  __shared__ float t[32][33];
  const int c0 = blockIdx.x * 32, r0 = blockIdx.y * 32;
  const int tx = threadIdx.x, ty = threadIdx.y;
#pragma unroll
  for (int k = 0; k < 4; k++)
    t[ty + k * 8][tx] = in[(long)(r0 + ty + k * 8) * C + c0 + tx];
  __syncthreads();
#pragma unroll
  for (int k = 0; k < 4; k++) {
    int cr = ty + k * 8;
    out[(long)(c0 + cr) * R + r0 + tx] = f2bf(t[tx][cr]);
  }
}

// ---------- LayerNorm (row of 1024), optional bf16 out / context copy / fp32 out ----------
__global__ __launch_bounds__(256) void ln_k(const float* __restrict__ x,
                                            const float* __restrict__ gw,
                                            const float* __restrict__ bw,
                                            u16* __restrict__ xn_out,
                                            float* __restrict__ ctx_out,
                                            float* __restrict__ f32_out, int layer) {
  const int row = blockIdx.x;
  const int tid = threadIdx.x;
  const float4 v = ((const float4*)(x + (long)row * 1024))[tid];
  float s = v.x + v.y + v.z + v.w;
  float ss = v.x * v.x + v.y * v.y + v.z * v.z + v.w * v.w;
#pragma unroll
  for (int o = 1; o < 64; o <<= 1) { s += __shfl_xor(s, o); ss += __shfl_xor(ss, o); }
  __shared__ float sb[8];
  const int wv = tid >> 6, ln = tid & 63;
  if (ln == 0) { sb[wv] = s; sb[4 + wv] = ss; }
  __syncthreads();
  s = sb[0] + sb[1] + sb[2] + sb[3];
  ss = sb[4] + sb[5] + sb[6] + sb[7];
  const float mean = s * (1.0f / 1024.0f);
  const float var = ss * (1.0f / 1024.0f) - mean * mean;
  const float rs = rsqrtf(var + 1e-5f);
  const int c = tid * 4;
  const float o0 = (v.x - mean) * rs * gw[c + 0] + bw[c + 0];
  const float o1 = (v.y - mean) * rs * gw[c + 1] + bw[c + 1];
  const float o2 = (v.z - mean) * rs * gw[c + 2] + bw[c + 2];
  const float o3 = (v.w - mean) * rs * gw[c + 3] + bw[c + 3];
  if (xn_out) {
    ushort4 pk = make_ushort4(f2bf(o0), f2bf(o1), f2bf(o2), f2bf(o3));
    *(ushort4*)(xn_out + (long)row * 1024 + c) = pk;
  }
  if (ctx_out) *(float4*)(ctx_out + ((long)row * 8 + layer) * 1024 + c) = v;
  if (f32_out) { float4 o = make_float4(o0, o1, o2, o3); *(float4*)(f32_out + (long)row * 1024 + c) = o; }
}

// ---------- causal softmax over bf16 scores + attention-map accumulation ----------
__global__ __launch_bounds__(256) void softmax_k(const u16* __restrict__ sc,
                                                 u16* __restrict__ pr,
                                                 float* __restrict__ amap) {
  const int rb = blockIdx.x, z = blockIdx.y;
  const int r0 = rb * 128;
  const int tid = threadIdx.x;
  const int lane = tid & 63, wv = tid >> 6;
  __shared__ float lmap[1024];
  for (int i = tid; i < 1024; i += 256) lmap[i] = 0.f;
  __syncthreads();
  const u16* S = sc + (long)z * 1048576;
  u16* P = pr + (long)z * 1048576;
  const int jcnt = r0 + 128;
  for (int rr = wv; rr < 128; rr += 4) {
    const int i = r0 + rr;
    const int len = i + 1;
    const long base = (long)i * 1024;
    float pv[16];
    float mx = -3.0e38f;
#pragma unroll
    for (int it = 0; it < 16; it++) {
      int j = it * 64 + lane;
      pv[it] = (j < len) ? bf2f(S[base + j]) : -3.0e38f;
      mx = fmaxf(mx, pv[it]);
    }
#pragma unroll
    for (int o = 1; o < 64; o <<= 1) mx = fmaxf(mx, __shfl_xor(mx, o));
    float sum = 0.f;
#pragma unroll
    for (int it = 0; it < 16; it++) {
      int j = it * 64 + lane;
      float e = (j < len) ? __expf(pv[it] - mx) : 0.f;
      pv[it] = e; sum += e;
    }
#pragma unroll
    for (int o = 1; o < 64; o <<= 1) sum += __shfl_xor(sum, o);
    const float inv = 1.0f / sum;
#pragma unroll
    for (int it = 0; it < 16; it++) {
      int j = it * 64 + lane;
      if (j < jcnt) {
        float val = (j < len) ? pv[it] * inv : 0.f;
        P[base + j] = f2bf(val);
        if (j < len) atomicAdd(&lmap[j], val);
      }
    }
  }
  __syncthreads();
  const int b = z >> 3;
  for (int c2 = tid; c2 < jcnt; c2 += 256) atomicAdd(&amap[b * 1024 + c2], lmap[c2]);
}

// ---------- 128x128 bf16 GEMM:  C = A[M][K] * Bt[N][K]^T, fp32 acc, per-EPI epilogue ----------
constexpr int EQ = 0, EKV = 1, ES = 2, EPV = 3, EWO = 4, EF1 = 5, EF2 = 6;

template <int EPI>
__global__ __launch_bounds__(256) void gemm128(const u16* __restrict__ A,
                                               const u16* __restrict__ Bt,
                                               long sA, long sB, int lda, int ldb, int K,
                                               void* __restrict__ out0, void* __restrict__ out1,
                                               const float* __restrict__ bias, float scale) {
  const int bn = blockIdx.x, bm = blockIdx.y, z = blockIdx.z;
  if (EPI == ES && bn > bm) return;   // fully-masked causal block
  const int Keff = (EPI == EPV) ? (bm + 1) * 128 : K;
  A += (long)z * sA;
  Bt += (long)z * sB;
  __shared__ __align__(16) u16 As[128 * 32];
  __shared__ __align__(16) u16 Bs[128 * 32];
  const int tid = threadIdx.x;
  const int lane = tid & 63;
  const int wv = tid >> 6;
  const int wm = (wv >> 1) * 64, wn = (wv & 1) * 64;
  f32x4 acc[4][4];
#pragma unroll
  for (int i = 0; i < 4; i++)
#pragma unroll
    for (int j = 0; j < 4; j++) acc[i][j] = (f32x4){0.f, 0.f, 0.f, 0.f};

  const int srow = tid >> 2;           // 0..63
  const int skoff = (tid & 3) * 8;     // k element offset
  const u16* ga = A + (long)(bm * 128 + srow) * lda + skoff;
  const u16* gb = Bt + (long)(bn * 128 + srow) * ldb + skoff;
  u16* lA = As + srow * 32 + skoff;
  u16* lB = Bs + srow * 32 + skoff;
  const int arow = wm + (lane & 15);
  const int brow = wn + (lane & 15);
  const int akk = (lane >> 4) * 8;

  for (int k0 = 0; k0 < Keff; k0 += 32) {
    __syncthreads();
    gload16(ga + k0, lA);
    gload16(ga + k0 + (long)64 * lda, lA + 64 * 32);
    gload16(gb + k0, lB);
    gload16(gb + k0 + (long)64 * ldb, lB + 64 * 32);
    __syncthreads();
    bf16x8 af[4], bfr[4];
#pragma unroll
    for (int i = 0; i < 4; i++) af[i] = *(const bf16x8*)(As + (arow + i * 16) * 32 + akk);
#pragma unroll
    for (int i = 0; i < 4; i++) bfr[i] = *(const bf16x8*)(Bs + (brow + i * 16) * 32 + akk);
#pragma unroll
    for (int mt = 0; mt < 4; mt++)
#pragma unroll
      for (int nt = 0; nt < 4; nt++)
        acc[mt][nt] = __builtin_amdgcn_mfma_f32_16x16x32_bf16(af[mt], bfr[nt], acc[mt][nt], 0, 0, 0);
  }

  const int lr = (lane >> 4) * 4;
  const int lc = lane & 15;
#pragma unroll
  for (int mt = 0; mt < 4; mt++)
#pragma unroll
    for (int nt = 0; nt < 4; nt++)
#pragma unroll
      for (int r = 0; r < 4; r++) {
        const int m = bm * 128 + wm + mt * 16 + lr + r;
        const int n = bn * 128 + wn + nt * 16 + lc;
        const float v = acc[mt][nt][r];
        if (EPI == EQ) {
          int b = m >> 10, s = m & 1023, h = n >> 7, hd = n & 127;
          ((u16*)out0)[((long)(b * 8 + h) * 1024 + s) * 128 + hd] = f2bf(v * scale);
        } else if (EPI == EKV) {
          int b = m >> 10, s = m & 1023, h = (n >> 7) & 7, hd = n & 127;
          if (n < 1024)
            ((u16*)out0)[((long)(b * 8 + h) * 1024 + s) * 128 + hd] = f2bf(v);
          else
            ((u16*)out1)[((long)(b * 8 + h) * 128 + hd) * 1024 + s] = f2bf(v);
        } else if (EPI == ES) {
          ((u16*)out0)[(long)z * 1048576 + (long)m * 1024 + n] = f2bf(v);
        } else if (EPI == EPV) {
          int b = z >> 3, h = z & 7;
          ((u16*)out0)[((long)b * 1024 + m) * 1024 + h * 128 + n] = f2bf(v);
        } else if (EPI == EWO) {
          float* X = (float*)out0;
          X[(long)m * 1024 + n] += v + bias[n];
        } else if (EPI == EF1) {
          float gl = 0.5f * v * (1.0f + erff(v * 0.70710678118654752f));
          ((u16*)out0)[(long)m * 4096 + n] = f2bf(gl);
        } else {  // EF2
          float* X = (float*)out0;
          X[(long)m * 1024 + n] += v;
        }
      }
}

// ---------- launch ----------
extern "C" void kernel_launch(void* const* d_in, const int* in_sizes, int n_in,
                              void* d_out, int out_size, void* d_ws, size_t ws_size,
                              hipStream_t stream) {
  (void)in_sizes; (void)n_in; (void)out_size; (void)ws_size;
  const float* token = (const float*)d_in[0];
  const float* Wq    = (const float*)d_in[1];
  const float* Wkv   = (const float*)d_in[2];
  const float* Wo    = (const float*)d_in[3];
  const float* b_o   = (const float*)d_in[4];
  const float* g1    = (const float*)d_in[5];
  const float* b1    = (const float*)d_in[6];
  const float* g3    = (const float*)d_in[7];
  const float* b3    = (const float*)d_in[8];
  const float* W1    = (const float*)d_in[9];
  const float* W2    = (const float*)d_in[10];
  const float* g_out = (const float*)d_in[11];
  const float* b_out = (const float*)d_in[12];

  float* out = (float*)d_out;
  char* w = (char*)d_ws;
  float* x   = (float*)(w + 0);            // 8 MB fp32 residual stream [2048][1024]
  u16* xn    = (u16*)(w + 8388608);        // bf16 [2048][1024]
  u16* q_a   = (u16*)(w + 12582912);       // bf16 [16][1024][128]
  u16* k_a   = (u16*)(w + 16777216);       // bf16 [16][1024][128]
  u16* vT    = (u16*)(w + 20971520);       // bf16 [16][128][1024]
  u16* y     = (u16*)(w + 25165824);       // bf16 [2048][1024]
  u16* h1    = (u16*)(w + 29360128);       // bf16 [2048][4096]
  u16* sc    = (u16*)(w + 46137344);       // bf16 [16][1024][1024]
  u16* pr    = (u16*)(w + 79691776);       // bf16 [16][1024][1024]
  u16* WqT   = (u16*)(w + 113246208);      // bf16 [1024][1024]
  u16* WkvT  = (u16*)(w + 115343360);      // bf16 [2048][1024]
  u16* WoT   = (u16*)(w + 119537664);      // bf16 [1024][1024]
  u16* W1T   = (u16*)(w + 121634816);      // bf16 [4096][1024]
  u16* W2T   = (u16*)(w + 130023424);      // bf16 [1024][4096]
  // total ws use: 138412032 bytes (132 MiB)

  float* xout  = out;                       // [2][1024][1024]
  float* state = out + 2097152;             // [2][1024][8][1024]
  float* amap  = out + 2097152 + 16777216;  // [2][1024]

  hipMemsetAsync(amap, 0, 2048 * sizeof(float), stream);
  hipMemcpyAsync(x, token, 8388608, hipMemcpyDeviceToDevice, stream);

  const float scale = 0.08838834764831845f;  // 1/sqrt(128)
  for (int l = 0; l < 8; l++) {
    tcast<<<dim3(32, 32), dim3(32, 8), 0, stream>>>(Wq + (long)l * 1048576, WqT, 1024, 1024);
    tcast<<<dim3(64, 32), dim3(32, 8), 0, stream>>>(Wkv + (long)l * 2097152, WkvT, 1024, 2048);
    tcast<<<dim3(32, 32), dim3(32, 8), 0, stream>>>(Wo + (long)l * 1048576, WoT, 1024, 1024);
    tcast<<<dim3(128, 32), dim3(32, 8), 0, stream>>>(W1 + (long)l * 4194304, W1T, 1024, 4096);
    tcast<<<dim3(32, 128), dim3(32, 8), 0, stream>>>(W2 + (long)l * 4194304, W2T, 4096, 1024);

    ln_k<<<2048, 256, 0, stream>>>(x, g1 + l * 1024, b1 + l * 1024, xn, state, nullptr, l);

    gemm128<EQ><<<dim3(8, 16, 1), 256, 0, stream>>>(xn, WqT, 0, 0, 1024, 1024, 1024,
                                                    q_a, nullptr, nullptr, scale);
    gemm128<EKV><<<dim3(16, 16, 1), 256, 0, stream>>>(xn, WkvT, 0, 0, 1024, 1024, 1024,
                                                      k_a, vT, nullptr, 0.f);
    gemm128<ES><<<dim3(8, 8, 16), 256, 0, stream>>>(q_a, k_a, 131072, 131072, 128, 128, 128,
                                                    sc, nullptr, nullptr, 0.f);
    softmax_k<<<dim3(8, 16), 256, 0, stream>>>(sc, pr, amap);
    gemm128<EPV><<<dim3(1, 8, 16), 256, 0, stream>>>(pr, vT, 1048576, 131072, 1024, 1024, 1024,
                                                     y, nullptr, nullptr, 0.f);
    gemm128<EWO><<<dim3(8, 16, 1), 256, 0, stream>>>(y, WoT, 0, 0, 1024, 1024, 1024,
                                                     x, nullptr, b_o + l * 1024, 0.f);

    ln_k<<<2048, 256, 0, stream>>>(x, g3 + l * 1024, b3 + l * 1024, xn, nullptr, nullptr, 0);

    gemm128<EF1><<<dim3(32, 16, 1), 256, 0, stream>>>(xn, W1T, 0, 0, 1024, 1024, 1024,
                                                      h1, nullptr, nullptr, 0.f);
    gemm128<EF2><<<dim3(8, 16, 1), 256, 0, stream>>>(h1, W2T, 0, 0, 4096, 4096, 4096,
                                                     x, nullptr, nullptr, 0.f);
  }
  ln_k<<<2048, 256, 0, stream>>>(x, g_out, b_out, nullptr, nullptr, xout, 0);
}

// Round 7
// 2474.685 us; speedup vs baseline: 1.7011x; 1.7011x over previous
//
#include <hip/hip_runtime.h>

typedef unsigned short u16;
typedef __attribute__((ext_vector_type(8))) short bf16x8;
typedef __attribute__((ext_vector_type(8))) unsigned short u16x8;
typedef __attribute__((ext_vector_type(4))) float f32x4;

// ---------- helpers ----------
__device__ __forceinline__ float bf2f(u16 u) {
  union { unsigned u; float f; } c; c.u = ((unsigned)u) << 16; return c.f;
}
__device__ __forceinline__ u16 f2bf(float f) {
  union { float f; unsigned u; } c; c.f = f;
  unsigned r = (c.u + 0x7fffu + ((c.u >> 16) & 1u)) >> 16;
  return (u16)r;
}
__device__ __forceinline__ void gload16(const u16* g, u16* l) {
  __builtin_amdgcn_global_load_lds((__attribute__((address_space(1))) void*)(g),
                                   (__attribute__((address_space(3))) void*)(l), 16, 0, 0);
}

// ---------- transpose + fp32->bf16 cast:  in[R][C] fp32 -> out[C][R] bf16 ----------
__global__ __launch_bounds__(256) void tcast(const float* __restrict__ in,
                                             u16* __restrict__ out, int R, int C) {
  __shared__ float t[32][33];
  const int c0 = blockIdx.x * 32, r0 = blockIdx.y * 32;
  const int tx = threadIdx.x, ty = threadIdx.y;
#pragma unroll
  for (int k = 0; k < 4; k++)
    t[ty + k * 8][tx] = in[(long)(r0 + ty + k * 8) * C + c0 + tx];
  __syncthreads();
#pragma unroll
  for (int k = 0; k < 4; k++) {
    int cr = ty + k * 8;
    out[(long)(c0 + cr) * R + r0 + tx] = f2bf(t[tx][cr]);
  }
}

// ---------- LayerNorm (row of 1024), optional bf16 out / context copy / fp32 out ----------
__global__ __launch_bounds__(256) void ln_k(const float* __restrict__ x,
                                            const float* __restrict__ gw,
                                            const float* __restrict__ bw,
                                            u16* __restrict__ xn_out,
                                            float* __restrict__ ctx_out,
                                            float* __restrict__ f32_out, int layer) {
  const int row = blockIdx.x;
  const int tid = threadIdx.x;
  const float4 v = ((const float4*)(x + (long)row * 1024))[tid];
  float s = v.x + v.y + v.z + v.w;
  float ss = v.x * v.x + v.y * v.y + v.z * v.z + v.w * v.w;
#pragma unroll
  for (int o = 1; o < 64; o <<= 1) { s += __shfl_xor(s, o); ss += __shfl_xor(ss, o); }
  __shared__ float sb[8];
  const int wv = tid >> 6, ln = tid & 63;
  if (ln == 0) { sb[wv] = s; sb[4 + wv] = ss; }
  __syncthreads();
  s = sb[0] + sb[1] + sb[2] + sb[3];
  ss = sb[4] + sb[5] + sb[6] + sb[7];
  const float mean = s * (1.0f / 1024.0f);
  const float var = ss * (1.0f / 1024.0f) - mean * mean;
  const float rs = rsqrtf(var + 1e-5f);
  const int c = tid * 4;
  const float o0 = (v.x - mean) * rs * gw[c + 0] + bw[c + 0];
  const float o1 = (v.y - mean) * rs * gw[c + 1] + bw[c + 1];
  const float o2 = (v.z - mean) * rs * gw[c + 2] + bw[c + 2];
  const float o3 = (v.w - mean) * rs * gw[c + 3] + bw[c + 3];
  if (xn_out) {
    ushort4 pk = make_ushort4(f2bf(o0), f2bf(o1), f2bf(o2), f2bf(o3));
    *(ushort4*)(xn_out + (long)row * 1024 + c) = pk;
  }
  if (ctx_out) *(float4*)(ctx_out + ((long)row * 8 + layer) * 1024 + c) = v;
  if (f32_out) { float4 o = make_float4(o0, o1, o2, o3); *(float4*)(f32_out + (long)row * 1024 + c) = o; }
}

// ---------- causal softmax, 16 rows/block, vectorized; partial column sums to scratch ----------
__global__ __launch_bounds__(256) void softmax_k(const u16* __restrict__ sc,
                                                 u16* __restrict__ pr,
                                                 float* __restrict__ part) {
  const int rb = blockIdx.x, z = blockIdx.y;   // rb: 0..63 (16-row groups), z: 0..15
  const int tid = threadIdx.x;
  const int lane = tid & 63, wv = tid >> 6;
  __shared__ float lmap[1024];
  for (int i = tid; i < 1024; i += 256) lmap[i] = 0.f;
  __syncthreads();
  const u16* S = sc + (long)z * 1048576;
  u16* P = pr + (long)z * 1048576;
  const int r0 = rb * 16;
  const int jcnt = ((r0 >> 7) + 1) * 128;      // PV reads this many cols for these rows
  float ca[16];
#pragma unroll
  for (int t = 0; t < 16; t++) ca[t] = 0.f;
  const int j0a = lane * 8, j0b = 512 + lane * 8;

  for (int rr = 0; rr < 4; rr++) {
    const int i = r0 + wv * 4 + rr;
    const int len = i + 1;
    const long base = (long)i * 1024;
    float pv[16];
    float mx = -3.0e38f;
    if (j0a < jcnt) {
      u16x8 va = *(const u16x8*)(S + base + j0a);
#pragma unroll
      for (int e = 0; e < 8; e++) {
        int j = j0a + e;
        pv[e] = (j < len) ? bf2f(va[e]) : -3.0e38f;
        mx = fmaxf(mx, pv[e]);
      }
    } else {
#pragma unroll
      for (int e = 0; e < 8; e++) pv[e] = -3.0e38f;
    }
    if (j0b < jcnt) {
      u16x8 vb = *(const u16x8*)(S + base + j0b);
#pragma unroll
      for (int e = 0; e < 8; e++) {
        int j = j0b + e;
        pv[8 + e] = (j < len) ? bf2f(vb[e]) : -3.0e38f;
        mx = fmaxf(mx, pv[8 + e]);
      }
    } else {
#pragma unroll
      for (int e = 0; e < 8; e++) pv[8 + e] = -3.0e38f;
    }
#pragma unroll
    for (int o = 1; o < 64; o <<= 1) mx = fmaxf(mx, __shfl_xor(mx, o));
    float sum = 0.f;
#pragma unroll
    for (int t = 0; t < 16; t++) {
      int j = (t < 8) ? (j0a + t) : (j0b + t - 8);
      float e = (j < len) ? __expf(pv[t] - mx) : 0.f;
      pv[t] = e; sum += e;
    }
#pragma unroll
    for (int o = 1; o < 64; o <<= 1) sum += __shfl_xor(sum, o);
    const float inv = 1.0f / sum;
    if (j0a < jcnt) {
      u16x8 st;
#pragma unroll
      for (int e = 0; e < 8; e++) {
        float val = pv[e] * inv;
        ca[e] += val;
        st[e] = f2bf(val);
      }
      *(u16x8*)(P + base + j0a) = st;
    }
    if (j0b < jcnt) {
      u16x8 st;
#pragma unroll
      for (int e = 0; e < 8; e++) {
        float val = pv[8 + e] * inv;
        ca[8 + e] += val;
        st[e] = f2bf(val);
      }
      *(u16x8*)(P + base + j0b) = st;
    }
  }
#pragma unroll
  for (int e = 0; e < 8; e++) {
    if (ca[e] != 0.f) atomicAdd(&lmap[j0a + e], ca[e]);
    if (ca[8 + e] != 0.f) atomicAdd(&lmap[j0b + e], ca[8 + e]);
  }
  __syncthreads();
  float* pb = part + ((long)z * 64 + rb) * 1024;
  for (int j = tid; j < 1024; j += 256) pb[j] = lmap[j];
}

// ---------- amap partial reduce: block z handles head h=z; atomicAdd per column ----------
__global__ __launch_bounds__(256) void amap_reduce(const float* __restrict__ part,
                                                   float* __restrict__ amap) {
  const int j = blockIdx.x * 256 + threadIdx.x;
  const int b = blockIdx.y;
  const int h = blockIdx.z;
  float s = 0.f;
  for (int rb = 0; rb < 64; rb++) {
    s += part[((long)((b * 8 + h) * 64 + rb)) * 1024 + j];
  }
  atomicAdd(&amap[b * 1024 + j], s);
}

// ---------- 128x128 bf16 GEMM:  C = A[M][K] * Bt[N][K]^T, fp32 acc, per-EPI epilogue ----------
// EWO/EF2 use blockIdx.z as a 2-way split-K index with atomicAdd epilogue.
constexpr int EQKV = 0, ES = 2, EPV = 3, EWO = 4, EF1 = 5, EF2 = 6;

template <int EPI>
__global__ __launch_bounds__(256) void gemm128(const u16* __restrict__ A,
                                               const u16* __restrict__ Bt,
                                               long sA, long sB, int lda, int ldb, int K,
                                               void* __restrict__ out0, void* __restrict__ out1,
                                               void* __restrict__ out2,
                                               const float* __restrict__ bias, float scale) {
  const int bn = blockIdx.x, bm = blockIdx.y, z = blockIdx.z;
  if (EPI == ES && bn > bm) return;   // fully-masked causal block
  int k_lo = 0, k_hi = K;
  if (EPI == EPV) k_hi = (bm + 1) * 128;                      // causal K-limit
  if (EPI == EWO || EPI == EF2) { k_lo = z * (K >> 1); k_hi = k_lo + (K >> 1); }  // split-K
  A += (long)z * sA;
  Bt += (long)z * sB;
  __shared__ __align__(16) u16 As[128 * 32];
  __shared__ __align__(16) u16 Bs[128 * 32];
  const int tid = threadIdx.x;
  const int lane = tid & 63;
  const int wv = tid >> 6;
  const int wm = (wv >> 1) * 64, wn = (wv & 1) * 64;
  f32x4 acc[4][4];
#pragma unroll
  for (int i = 0; i < 4; i++)
#pragma unroll
    for (int j = 0; j < 4; j++) acc[i][j] = (f32x4){0.f, 0.f, 0.f, 0.f};

  const int srow = tid >> 2;           // 0..63
  const int skoff = (tid & 3) * 8;     // k element offset
  const u16* ga = A + (long)(bm * 128 + srow) * lda + skoff;
  const u16* gb = Bt + (long)(bn * 128 + srow) * ldb + skoff;
  u16* lA = As + srow * 32 + skoff;
  u16* lB = Bs + srow * 32 + skoff;
  const int arow = wm + (lane & 15);
  const int brow = wn + (lane & 15);
  const int akk = (lane >> 4) * 8;

  for (int k0 = k_lo; k0 < k_hi; k0 += 32) {
    __syncthreads();
    gload16(ga + k0, lA);
    gload16(ga + k0 + (long)64 * lda, lA + 64 * 32);
    gload16(gb + k0, lB);
    gload16(gb + k0 + (long)64 * ldb, lB + 64 * 32);
    __syncthreads();
    bf16x8 af[4], bfr[4];
#pragma unroll
    for (int i = 0; i < 4; i++) af[i] = *(const bf16x8*)(As + (arow + i * 16) * 32 + akk);
#pragma unroll
    for (int i = 0; i < 4; i++) bfr[i] = *(const bf16x8*)(Bs + (brow + i * 16) * 32 + akk);
#pragma unroll
    for (int mt = 0; mt < 4; mt++)
#pragma unroll
      for (int nt = 0; nt < 4; nt++)
        acc[mt][nt] = __builtin_amdgcn_mfma_f32_16x16x32_bf16(af[mt], bfr[nt], acc[mt][nt], 0, 0, 0);
  }

  const int lr = (lane >> 4) * 4;
  const int lc = lane & 15;
#pragma unroll
  for (int mt = 0; mt < 4; mt++)
#pragma unroll
    for (int nt = 0; nt < 4; nt++)
#pragma unroll
      for (int r = 0; r < 4; r++) {
        const int m = bm * 128 + wm + mt * 16 + lr + r;
        const int n = bn * 128 + wn + nt * 16 + lc;
        const float v = acc[mt][nt][r];
        if (EPI == EQKV) {
          int b = m >> 10, s = m & 1023, hd = n & 127;
          if (n < 1024) {
            int h = n >> 7;
            ((u16*)out0)[((long)(b * 8 + h) * 1024 + s) * 128 + hd] = f2bf(v * scale);
          } else if (n < 2048) {
            int h = (n >> 7) & 7;
            ((u16*)out1)[((long)(b * 8 + h) * 1024 + s) * 128 + hd] = f2bf(v);
          } else {
            int h = (n >> 7) & 7;
            ((u16*)out2)[((long)(b * 8 + h) * 128 + hd) * 1024 + s] = f2bf(v);
          }
        } else if (EPI == ES) {
          ((u16*)out0)[(long)z * 1048576 + (long)m * 1024 + n] = f2bf(v);
        } else if (EPI == EPV) {
          int b = z >> 3, h = z & 7;
          ((u16*)out0)[((long)b * 1024 + m) * 1024 + h * 128 + n] = f2bf(v);
        } else if (EPI == EWO) {
          float* X = (float*)out0;
          float add = v + (z == 0 ? bias[n] : 0.f);
          atomicAdd(&X[(long)m * 1024 + n], add);
        } else if (EPI == EF1) {
          float gl = 0.5f * v * (1.0f + erff(v * 0.70710678118654752f));
          ((u16*)out0)[(long)m * 4096 + n] = f2bf(gl);
        } else {  // EF2
          atomicAdd(&((float*)out0)[(long)m * 1024 + n], v);
        }
      }
}

// ---------- launch ----------
extern "C" void kernel_launch(void* const* d_in, const int* in_sizes, int n_in,
                              void* d_out, int out_size, void* d_ws, size_t ws_size,
                              hipStream_t stream) {
  (void)in_sizes; (void)n_in; (void)out_size; (void)ws_size;
  const float* token = (const float*)d_in[0];
  const float* Wq    = (const float*)d_in[1];
  const float* Wkv   = (const float*)d_in[2];
  const float* Wo    = (const float*)d_in[3];
  const float* b_o   = (const float*)d_in[4];
  const float* g1    = (const float*)d_in[5];
  const float* b1    = (const float*)d_in[6];
  const float* g3    = (const float*)d_in[7];
  const float* b3    = (const float*)d_in[8];
  const float* W1    = (const float*)d_in[9];
  const float* W2    = (const float*)d_in[10];
  const float* g_out = (const float*)d_in[11];
  const float* b_out = (const float*)d_in[12];

  float* out = (float*)d_out;
  char* w = (char*)d_ws;
  float* x   = (float*)(w + 0);            // 8 MB fp32 residual stream [2048][1024]
  u16* xn    = (u16*)(w + 8388608);        // bf16 [2048][1024]
  u16* q_a   = (u16*)(w + 12582912);       // bf16 [16][1024][128]
  u16* k_a   = (u16*)(w + 16777216);       // bf16 [16][1024][128]
  u16* vT    = (u16*)(w + 20971520);       // bf16 [16][128][1024]
  u16* y     = (u16*)(w + 25165824);       // bf16 [2048][1024]
  u16* h1    = (u16*)(w + 29360128);       // bf16 [2048][4096]
  u16* sc    = (u16*)(w + 46137344);       // bf16 [16][1024][1024]
  u16* pr    = (u16*)(w + 79691776);       // bf16 [16][1024][1024]
  u16* WqT   = (u16*)(w + 113246208);      // bf16 [1024][1024]  (contiguous with WkvT!)
  u16* WkvT  = (u16*)(w + 115343360);      // bf16 [2048][1024]
  u16* WoT   = (u16*)(w + 119537664);      // bf16 [1024][1024]
  u16* W1T   = (u16*)(w + 121634816);      // bf16 [4096][1024]
  u16* W2T   = (u16*)(w + 130023424);      // bf16 [1024][4096]
  float* part = (float*)(w + 138412032);   // fp32 [16][64][1024] partial col sums (4 MB)
  // total ws use: 142606336 bytes (136 MiB)

  float* xout  = out;                       // [2][1024][1024]
  float* state = out + 2097152;             // [2][1024][8][1024]
  float* amap  = out + 2097152 + 16777216;  // [2][1024]

  hipMemsetAsync(amap, 0, 2048 * sizeof(float), stream);
  hipMemcpyAsync(x, token, 8388608, hipMemcpyDeviceToDevice, stream);

  const float scale = 0.08838834764831845f;  // 1/sqrt(128)
  for (int l = 0; l < 8; l++) {
    tcast<<<dim3(32, 32), dim3(32, 8), 0, stream>>>(Wq + (long)l * 1048576, WqT, 1024, 1024);
    tcast<<<dim3(64, 32), dim3(32, 8), 0, stream>>>(Wkv + (long)l * 2097152, WkvT, 1024, 2048);
    tcast<<<dim3(32, 32), dim3(32, 8), 0, stream>>>(Wo + (long)l * 1048576, WoT, 1024, 1024);
    tcast<<<dim3(128, 32), dim3(32, 8), 0, stream>>>(W1 + (long)l * 4194304, W1T, 1024, 4096);
    tcast<<<dim3(32, 128), dim3(32, 8), 0, stream>>>(W2 + (long)l * 4194304, W2T, 4096, 1024);

    ln_k<<<2048, 256, 0, stream>>>(x, g1 + l * 1024, b1 + l * 1024, xn, state, nullptr, l);

    // fused Q + KV projection: B = [WqT; WkvT] (3072 x 1024), one launch
    gemm128<EQKV><<<dim3(24, 16, 1), 256, 0, stream>>>(xn, WqT, 0, 0, 1024, 1024, 1024,
                                                       q_a, k_a, vT, nullptr, scale);
    gemm128<ES><<<dim3(8, 8, 16), 256, 0, stream>>>(q_a, k_a, 131072, 131072, 128, 128, 128,
                                                    sc, nullptr, nullptr, nullptr, 0.f);
    softmax_k<<<dim3(64, 16), 256, 0, stream>>>(sc, pr, part);
    amap_reduce<<<dim3(4, 2, 8), 256, 0, stream>>>(part, amap);
    gemm128<EPV><<<dim3(1, 8, 16), 256, 0, stream>>>(pr, vT, 1048576, 131072, 1024, 1024, 1024,
                                                     y, nullptr, nullptr, nullptr, 0.f);
    gemm128<EWO><<<dim3(8, 16, 2), 256, 0, stream>>>(y, WoT, 0, 0, 1024, 1024, 1024,
                                                     x, nullptr, nullptr, b_o + l * 1024, 0.f);

    ln_k<<<2048, 256, 0, stream>>>(x, g3 + l * 1024, b3 + l * 1024, xn, nullptr, nullptr, 0);

    gemm128<EF1><<<dim3(32, 16, 1), 256, 0, stream>>>(xn, W1T, 0, 0, 1024, 1024, 1024,
                                                      h1, nullptr, nullptr, nullptr, 0.f);
    gemm128<EF2><<<dim3(8, 16, 2), 256, 0, stream>>>(h1, W2T, 0, 0, 4096, 4096, 4096,
                                                     x, nullptr, nullptr, nullptr, 0.f);
  }
  ln_k<<<2048, 256, 0, stream>>>(x, g_out, b_out, nullptr, nullptr, xout, 0);
}